// Round 10
// baseline (373.431 us; speedup 1.0000x reference)
//
#include <hip/hip_runtime.h>
#include <hip/hip_bf16.h>

#define H 4096
#define NEXP 256
#define TOPK 8
#define NGROUP 8
#define TOPKG 4
#define ROUTED_SCALING 2.5f
#define WSCALE 1024.0f
#define INV_WSCALE (1.0f / 1024.0f)

#define PART_OFF ((size_t)4 * 1024 * 1024)
#define WS_NEED  (PART_OFF + (size_t)512 * 65536)   // 4MB wfrags + 32MB partials

typedef __attribute__((ext_vector_type(8)))  _Float16 f16x8;
typedef __attribute__((ext_vector_type(16))) float    f32x16;
typedef __attribute__((ext_vector_type(4)))  float    f32x4;

// ============================================================================
// Pre-kernel: split W*1024 into 2 fp16 levels in 32x32x16 B-fragment order.
// level v at ws + v*2MB; frag addr = ((etile*256+ks)*64+lane)*16.
// ============================================================================
__global__ __launch_bounds__(256) void wsplit_kernel(
    const float* __restrict__ W, char* __restrict__ ws)
{
    const int t  = blockIdx.x * 256 + threadIdx.x;
    const int l  = t & 63;
    const int ks = (t >> 6) & 255;
    const int eg = t >> 14;
    const int expert = eg * 32 + (l & 31);
    const int k0 = ks * 16 + (l >> 5) * 8;
    const float* src = W + (size_t)expert * H + k0;
    float xf[8];
    *(float4*)&xf[0] = *(const float4*)(src);
    *(float4*)&xf[4] = *(const float4*)(src + 4);
    union { _Float16 h[8]; int4 q; } o1, o2;
#pragma unroll
    for (int j = 0; j < 8; ++j) {
        const float x = xf[j] * WSCALE;
        const _Float16 h1 = (_Float16)x;
        o1.h[j] = h1;
        o2.h[j] = (_Float16)(x - (float)h1);
    }
    const size_t off = ((size_t)((eg * 256 + ks) * 64 + l)) * 16;
    *(int4*)(ws + off)           = o1.q;
    *(int4*)(ws + 2097152 + off) = o2.q;
}

// ============================================================================
// Kernel A (v4): 512 blocks x 512 thr (2 blocks/CU, 16 waves/CU).
// Block (mt = bid>>1, kb = bid&1): 64 tokens x 256 experts x half-K (2048).
// kb = bid&1 is constant per XCD (round-robin bid%8) -> per-XCD B working
// set = 2MB = half of per-XCD L2 -> W frags stay L2-resident under X stream.
// A: X nt-loads (each line once device-wide) -> fp16x2 split once -> LDS.
// B: 4-deep register ring, unconditional loads (tail over-read lands in the
// partials region - valid, unused). Slice barrier = lgkmcnt + raw s_barrier.
// Numerics as v3 (proven): x1w1 -> acc_hi drained to fp32 tot per slice;
// x1w2+x2w1 chained in acc_rest. Partial = tot + acc_rest (fp32) to ws.
// ============================================================================
__global__ __launch_bounds__(512, 4) void moe_partial_v4(
    const float* __restrict__ X, char* ws, int T)
{
    __shared__ __align__(16) char SM[65536];
    const int tid = threadIdx.x;
    const int l   = tid & 63;
    const int eg  = tid >> 6;        // wave id = expert tile 0..7
    const int sks = tid >> 6;        // staging ks-slot 0..7
    const int bid = blockIdx.x;
    const int kb  = bid & 1;         // K-half
    const int mt  = bid >> 1;        // M-tile
    const int m0  = mt * 64;

#define XA_OFF(buf, lvl, ks, m) (((((buf) * 2 + (lvl)) * 8 + (ks)) * 2 + (m)) * 1024)

    const float* Xs_base = X + (size_t)(m0 + (l & 31)) * H
                             + kb * 2048 + sks * 16 + 8 * (l >> 5);
    const char*  bp      = ws + (size_t)eg * 262144
                              + (size_t)(kb * 128) * 1024 + (size_t)l * 16;

    f32x16 acc_hi[2], acc_rest[2], tot[2];
#pragma unroll
    for (int m = 0; m < 2; ++m)
#pragma unroll
        for (int r = 0; r < 16; ++r) {
            acc_hi[m][r] = 0.f; acc_rest[m][r] = 0.f; tot[m][r] = 0.f;
        }

    f32x4 xr[2][2];
    union BF { int4 q; f16x8 v; };
    BF rb[4][2];

#define XISSUE(s)                                                          \
    { _Pragma("unroll")                                                    \
      for (int m = 0; m < 2; ++m) {                                        \
        const float* p_ = Xs_base + (size_t)(s) * 128 + (size_t)m * 32 * H;\
        xr[m][0] = __builtin_nontemporal_load((const f32x4*)p_);           \
        xr[m][1] = __builtin_nontemporal_load((const f32x4*)(p_ + 4));     \
      } }

#define XWRITE(buf)                                                       \
    { _Pragma("unroll")                                                    \
      for (int m = 0; m < 2; ++m) {                                        \
        union { int4 q; _Float16 h[8]; } w1_, w2_;                        \
        _Pragma("unroll")                                                  \
        for (int j = 0; j < 8; ++j) {                                      \
            const float x_ = (j < 4) ? xr[m][0][j] : xr[m][1][j - 4];      \
            const _Float16 h1_ = (_Float16)x_;                             \
            w1_.h[j] = h1_;                                                \
            w2_.h[j] = (_Float16)(x_ - (float)h1_);                        \
        }                                                                  \
        *(int4*)(SM + XA_OFF(buf, 0, sks, m) + l * 16) = w1_.q;            \
        *(int4*)(SM + XA_OFF(buf, 1, sks, m) + l * 16) = w2_.q;            \
      } }

#define SLICE_BARRIER()                                                    \
    { asm volatile("s_waitcnt lgkmcnt(0)" ::: "memory");                   \
      __builtin_amdgcn_s_barrier();                                        \
      asm volatile("" ::: "memory"); }

    XISSUE(0)
    XWRITE(0)
    __syncthreads();
    XISSUE(1)
#pragma unroll
    for (int i = 0; i < 4; ++i) {
        rb[i][0].q = *(const int4*)(bp + (size_t)i * 1024);
        rb[i][1].q = *(const int4*)(bp + 2097152 + (size_t)i * 1024);
    }

    int cur = 0;
    for (int s = 0; s < 16; ++s) {
        const int kbase = s * 8;
#pragma unroll
        for (int i = 0; i < 8; ++i) {
            union { int4 q; f16x8 v; } a1[2], a2[2];
#pragma unroll
            for (int m = 0; m < 2; ++m) {
                a1[m].q = *(const int4*)(SM + XA_OFF(cur, 0, i, m) + l * 16);
                a2[m].q = *(const int4*)(SM + XA_OFF(cur, 1, i, m) + l * 16);
            }
#pragma unroll
            for (int m = 0; m < 2; ++m) {
                acc_hi[m] = __builtin_amdgcn_mfma_f32_32x32x16_f16(
                    a1[m].v, rb[i & 3][0].v, acc_hi[m], 0, 0, 0);
                acc_rest[m] = __builtin_amdgcn_mfma_f32_32x32x16_f16(
                    a1[m].v, rb[i & 3][1].v, acc_rest[m], 0, 0, 0);
                acc_rest[m] = __builtin_amdgcn_mfma_f32_32x32x16_f16(
                    a2[m].v, rb[i & 3][0].v, acc_rest[m], 0, 0, 0);
            }
            // unconditional prefetch (tail over-read is in-bounds of ws, unused)
            const int kn = kbase + i + 4;
            rb[i & 3][0].q = *(const int4*)(bp + (size_t)kn * 1024);
            rb[i & 3][1].q = *(const int4*)(bp + 2097152 + (size_t)kn * 1024);
        }
#pragma unroll
        for (int m = 0; m < 2; ++m)
#pragma unroll
            for (int r = 0; r < 16; ++r) { tot[m][r] += acc_hi[m][r]; acc_hi[m][r] = 0.f; }
        if (s + 1 < 16) {
            XWRITE(cur ^ 1)
            SLICE_BARRIER()
            if (s + 2 < 16) XISSUE(s + 2)
            cur ^= 1;
        }
    }
#undef XISSUE
#undef XWRITE
#undef SLICE_BARRIER

    // write fp32 partial logits: layout idx = ((eg*16 + r)*2 + m)*64 + l
    float* pp = (float*)(ws + PART_OFF) + (size_t)(mt * 2 + kb) * 16384;
#pragma unroll
    for (int m = 0; m < 2; ++m)
#pragma unroll
        for (int r = 0; r < 16; ++r)
            pp[((eg * 16 + r) * 2 + m) * 64 + l] = tot[m][r] + acc_rest[m][r];
}

// ============================================================================
// Kernel B (v4): 256 blocks x 256 thr. Combine both K-half partials (fp32 add,
// commutative -> deterministic), sigmoid+bias into swizzled SC, then the
// proven v3 gating epilogue for 64 tokens.
// ============================================================================
__global__ __launch_bounds__(256) void moe_gate_v4(
    const char* __restrict__ ws, const float* __restrict__ bias,
    float* __restrict__ out, int T)
{
    __shared__ float SC[NEXP * 64];   // 64 KB
    const int tid = threadIdx.x;
    const int mt  = blockIdx.x;
    const int m0  = mt * 64;
    const float* p0 = (const float*)(ws + PART_OFF) + (size_t)(mt * 2) * 16384;
    const float* p1 = p0 + 16384;

#pragma unroll 8
    for (int j = 0; j < 64; ++j) {
        const int i  = tid + 256 * j;
        const int l  = i & 63;
        const int m  = (i >> 6) & 1;
        const int r  = (i >> 7) & 15;
        const int eg = i >> 11;
        const int e  = 32 * eg + (l & 31);
        const int ti = 32 * m + (r & 3) + 8 * (r >> 2) + 4 * (l >> 5);
        const float logit = (p0[i] + p1[i]) * INV_WSCALE;
        const float sv = 1.0f / (1.0f + expf(-logit));
        SC[e * 64 + (ti ^ (e & 31))] = sv + bias[e];
    }
    __syncthreads();

    if (tid < 64) {
        const int t = tid;
        float gs[NGROUP];
#pragma unroll
        for (int g = 0; g < NGROUP; ++g) {
            float m1 = -1e30f, m2 = -1e30f;
            for (int j = 0; j < 32; ++j) {
                const int e = g * 32 + j;
                const float v = SC[e * 64 + (t ^ (e & 31))];
                if (v > m1) { m2 = m1; m1 = v; }
                else if (v > m2) { m2 = v; }
            }
            gs[g] = m1 + m2;
        }
        unsigned gmask = 0;
        for (int r = 0; r < TOPKG; ++r) {
            int bi = 0; float bv = -1e30f;
#pragma unroll
            for (int g = 0; g < NGROUP; ++g)
                if (!((gmask >> g) & 1u) && gs[g] > bv) { bv = gs[g]; bi = g; }
            gmask |= (1u << bi);
        }
        int glist[TOPKG], ng = 0;
#pragma unroll
        for (int g = 0; g < NGROUP; ++g)
            if ((gmask >> g) & 1u) glist[ng++] = g;
        int eidx[TOPK]; float sval[TOPK];
        unsigned cmask[TOPKG] = {0u, 0u, 0u, 0u};
        float wsum = 0.f;
        for (int r = 0; r < TOPK; ++r) {
            float bv = -1e30f; int bgi = 0, bj = 0;
            for (int gi = 0; gi < TOPKG; ++gi) {
                const int g = glist[gi];
                for (int j = 0; j < 32; ++j) {
                    if ((cmask[gi] >> j) & 1u) continue;
                    const int e = g * 32 + j;
                    const float v = SC[e * 64 + (t ^ (e & 31))];
                    if (v > bv) { bv = v; bgi = gi; bj = j; }
                }
            }
            cmask[bgi] |= (1u << bj);
            const int e = glist[bgi] * 32 + bj;
            eidx[r] = e;
            const float sig = bv - bias[e];
            sval[r] = sig; wsum += sig;
        }
        const float scale = ROUTED_SCALING / (wsum + 1e-20f);
        const size_t gt = (size_t)(m0 + t);
#pragma unroll
        for (int r = 0; r < TOPK; ++r) {
            out[gt * TOPK + r] = (float)eidx[r];
            out[(size_t)T * TOPK + gt * TOPK + r] = sval[r] * scale;
        }
    }
}

// ============================================================================
// Fallback v3 (verified round-9): 256 blocks x 512 thr, full-K per block.
// ============================================================================
__global__ __launch_bounds__(512, 2) void moe_mfma_v3(
    const float* __restrict__ X, const char* __restrict__ ws,
    const float* __restrict__ bias, float* __restrict__ out, int T)
{
    __shared__ __align__(16) char SM[65536];
    float* SC = (float*)SM;
    const int tid = threadIdx.x;
    const int l   = tid & 63;
    const int eg  = tid >> 6;
    const int sks = tid >> 6;
    const int m0  = blockIdx.x * 64;

    const float* Xs_base = X + (size_t)(m0 + (l & 31)) * H + sks * 16 + 8 * (l >> 5);
    const char*  bp      = ws + (size_t)eg * 262144 + (size_t)l * 16;

    f32x16 acc_hi[2], acc_rest[2], tot[2];
#pragma unroll
    for (int m = 0; m < 2; ++m)
#pragma unroll
        for (int r = 0; r < 16; ++r) {
            acc_hi[m][r] = 0.f; acc_rest[m][r] = 0.f; tot[m][r] = 0.f;
        }
    f32x4 xr[2][2];
    union BF { int4 q; f16x8 v; };
    BF rb[4][2];

#define XISSUE(s)                                                          \
    { _Pragma("unroll")                                                    \
      for (int m = 0; m < 2; ++m) {                                        \
        const float* p_ = Xs_base + (size_t)(s) * 128 + (size_t)m * 32 * H;\
        xr[m][0] = __builtin_nontemporal_load((const f32x4*)p_);           \
        xr[m][1] = __builtin_nontemporal_load((const f32x4*)(p_ + 4));     \
      } }
#define XWRITE(buf)                                                       \
    { _Pragma("unroll")                                                    \
      for (int m = 0; m < 2; ++m) {                                        \
        union { int4 q; _Float16 h[8]; } w1_, w2_;                        \
        _Pragma("unroll")                                                  \
        for (int j = 0; j < 8; ++j) {                                      \
            const float x_ = (j < 4) ? xr[m][0][j] : xr[m][1][j - 4];      \
            const _Float16 h1_ = (_Float16)x_;                             \
            w1_.h[j] = h1_;                                                \
            w2_.h[j] = (_Float16)(x_ - (float)h1_);                        \
        }                                                                  \
        *(int4*)(SM + XA_OFF(buf, 0, sks, m) + l * 16) = w1_.q;            \
        *(int4*)(SM + XA_OFF(buf, 1, sks, m) + l * 16) = w2_.q;            \
      } }
#define SLICE_BARRIER()                                                    \
    { asm volatile("s_waitcnt lgkmcnt(0)" ::: "memory");                   \
      __builtin_amdgcn_s_barrier();                                        \
      asm volatile("" ::: "memory"); }

    XISSUE(0)
    XWRITE(0)
    __syncthreads();
    XISSUE(1)
#pragma unroll
    for (int i = 0; i < 4; ++i) {
        rb[i][0].q = *(const int4*)(bp + (size_t)i * 1024);
        rb[i][1].q = *(const int4*)(bp + 2097152 + (size_t)i * 1024);
    }
    int cur = 0;
    for (int s = 0; s < 32; ++s) {
        const int kbase = s * 8;
#pragma unroll
        for (int i = 0; i < 8; ++i) {
            union { int4 q; f16x8 v; } a1[2], a2[2];
#pragma unroll
            for (int m = 0; m < 2; ++m) {
                a1[m].q = *(const int4*)(SM + XA_OFF(cur, 0, i, m) + l * 16);
                a2[m].q = *(const int4*)(SM + XA_OFF(cur, 1, i, m) + l * 16);
            }
#pragma unroll
            for (int m = 0; m < 2; ++m) {
                acc_hi[m] = __builtin_amdgcn_mfma_f32_32x32x16_f16(
                    a1[m].v, rb[i & 3][0].v, acc_hi[m], 0, 0, 0);
                acc_rest[m] = __builtin_amdgcn_mfma_f32_32x32x16_f16(
                    a1[m].v, rb[i & 3][1].v, acc_rest[m], 0, 0, 0);
                acc_rest[m] = __builtin_amdgcn_mfma_f32_32x32x16_f16(
                    a2[m].v, rb[i & 3][0].v, acc_rest[m], 0, 0, 0);
            }
            const int kn = kbase + i + 4;
            if (kn < 256) {
                rb[i & 3][0].q = *(const int4*)(bp + (size_t)kn * 1024);
                rb[i & 3][1].q = *(const int4*)(bp + 2097152 + (size_t)kn * 1024);
            }
        }
#pragma unroll
        for (int m = 0; m < 2; ++m)
#pragma unroll
            for (int r = 0; r < 16; ++r) { tot[m][r] += acc_hi[m][r]; acc_hi[m][r] = 0.f; }
        if (s + 1 < 32) {
            XWRITE(cur ^ 1)
            SLICE_BARRIER()
            if (s + 2 < 32) XISSUE(s + 2)
            cur ^= 1;
        }
    }
#undef XISSUE
#undef XWRITE
#undef SLICE_BARRIER

    __syncthreads();
    {
        const int e = 32 * eg + (l & 31);
        const float be = bias[e];
#pragma unroll
        for (int m = 0; m < 2; ++m)
#pragma unroll
            for (int r = 0; r < 16; ++r) {
                const int ti = 32 * m + (r & 3) + 8 * (r >> 2) + 4 * (l >> 5);
                const float logit = (tot[m][r] + acc_rest[m][r]) * INV_WSCALE;
                const float sv = 1.0f / (1.0f + expf(-logit));
                SC[e * 64 + (ti ^ (e & 31))] = sv + be;
            }
    }
    __syncthreads();
    if (tid < 64) {
        const int t = tid;
        float gs[NGROUP];
#pragma unroll
        for (int g = 0; g < NGROUP; ++g) {
            float m1 = -1e30f, m2 = -1e30f;
            for (int j = 0; j < 32; ++j) {
                const int e = g * 32 + j;
                const float v = SC[e * 64 + (t ^ (e & 31))];
                if (v > m1) { m2 = m1; m1 = v; }
                else if (v > m2) { m2 = v; }
            }
            gs[g] = m1 + m2;
        }
        unsigned gmask = 0;
        for (int r = 0; r < TOPKG; ++r) {
            int bi = 0; float bv = -1e30f;
#pragma unroll
            for (int g = 0; g < NGROUP; ++g)
                if (!((gmask >> g) & 1u) && gs[g] > bv) { bv = gs[g]; bi = g; }
            gmask |= (1u << bi);
        }
        int glist[TOPKG], ng = 0;
#pragma unroll
        for (int g = 0; g < NGROUP; ++g)
            if ((gmask >> g) & 1u) glist[ng++] = g;
        int eidx[TOPK]; float sval[TOPK];
        unsigned cmask[TOPKG] = {0u, 0u, 0u, 0u};
        float wsum = 0.f;
        for (int r = 0; r < TOPK; ++r) {
            float bv = -1e30f; int bgi = 0, bj = 0;
            for (int gi = 0; gi < TOPKG; ++gi) {
                const int g = glist[gi];
                for (int j = 0; j < 32; ++j) {
                    if ((cmask[gi] >> j) & 1u) continue;
                    const int e = g * 32 + j;
                    const float v = SC[e * 64 + (t ^ (e & 31))];
                    if (v > bv) { bv = v; bgi = gi; bj = j; }
                }
            }
            cmask[bgi] |= (1u << bj);
            const int e = glist[bgi] * 32 + bj;
            eidx[r] = e;
            const float sig = bv - bias[e];
            sval[r] = sig; wsum += sig;
        }
        const float scale = ROUTED_SCALING / (wsum + 1e-20f);
        const size_t gt = (size_t)(m0 + t);
#pragma unroll
        for (int r = 0; r < TOPK; ++r) {
            out[gt * TOPK + r] = (float)eidx[r];
            out[(size_t)T * TOPK + gt * TOPK + r] = sval[r] * scale;
        }
    }
}

// ============================================================================
// Fallback (round-3 fp32 kernel) if ws < 4MB.
// ============================================================================
#define BMF 32
#define BKF 32
#define WS_STRIDE 388
#define XS_STRIDE 36
#define WS_FLOATS (BKF * WS_STRIDE)
#define SMEM_FLOATS (WS_FLOATS + BKF * XS_STRIDE)

__global__ __launch_bounds__(256, 2) void moe_gate_f32(
    const float* __restrict__ X, const float* __restrict__ W,
    const float* __restrict__ bias, float* __restrict__ out, int T)
{
    __shared__ float smem[SMEM_FLOATS];
    float* Ws = smem;
    float* Xs = smem + WS_FLOATS;
    float* SC = smem;
    const int tid = threadIdx.x;
    const int tq  = tid >> 5;
    const int tx  = tid & 31;
    const int m0  = blockIdx.x * BMF;
    const int q  = tid & 7;
    const int sx = tid >> 3;
    float acc[4][8];
#pragma unroll
    for (int r = 0; r < 4; ++r)
#pragma unroll
        for (int c = 0; c < 8; ++c) acc[r][c] = 0.f;
    float4 xr, wr[8];
    const float* Xbase = X + (size_t)(m0 + sx) * H + 4 * q;
    const float* Wbase = W + (size_t)sx * H + 4 * q;
    auto loadTile = [&](int k0) {
        xr = *(const float4*)(Xbase + k0);
#pragma unroll
        for (int i = 0; i < 8; ++i)
            wr[i] = *(const float4*)(Wbase + (size_t)(32 * i) * H + k0);
    };
    auto storeTile = [&]() {
        Xs[(4 * q + 0) * XS_STRIDE + sx] = xr.x;
        Xs[(4 * q + 1) * XS_STRIDE + sx] = xr.y;
        Xs[(4 * q + 2) * XS_STRIDE + sx] = xr.z;
        Xs[(4 * q + 3) * XS_STRIDE + sx] = xr.w;
#pragma unroll
        for (int i = 0; i < 8; ++i) {
            const int e = sx + 32 * i;
            const int col = 12 * (e >> 3) + (e & 7);
            Ws[(4 * q + 0) * WS_STRIDE + col] = wr[i].x;
            Ws[(4 * q + 1) * WS_STRIDE + col] = wr[i].y;
            Ws[(4 * q + 2) * WS_STRIDE + col] = wr[i].z;
            Ws[(4 * q + 3) * WS_STRIDE + col] = wr[i].w;
        }
    };
    loadTile(0);
    for (int k0 = 0; k0 < H; k0 += BKF) {
        storeTile();
        __syncthreads();
        if (k0 + BKF < H) loadTile(k0 + BKF);
#pragma unroll 8
        for (int kk = 0; kk < BKF; ++kk) {
            float a[4], b[8];
            *(float4*)&a[0] = *(const float4*)&Xs[kk * XS_STRIDE + 4 * tq];
            *(float4*)&b[0] = *(const float4*)&Ws[kk * WS_STRIDE + 12 * tx];
            *(float4*)&b[4] = *(const float4*)&Ws[kk * WS_STRIDE + 12 * tx + 4];
#pragma unroll
            for (int r = 0; r < 4; ++r)
#pragma unroll
                for (int c = 0; c < 8; ++c)
                    acc[r][c] = fmaf(a[r], b[c], acc[r][c]);
        }
        __syncthreads();
    }
#pragma unroll
    for (int c = 0; c < 8; ++c) {
        const int e = 8 * tx + c;
        const float be = bias[e];
#pragma unroll
        for (int r = 0; r < 4; ++r) {
            const int t = 4 * tq + r;
            const float s = 1.0f / (1.0f + expf(-acc[r][c]));
            SC[e * 32 + (t ^ tx)] = s + be;
        }
    }
    __syncthreads();
    if (tid < BMF) {
        const int t = tid;
        float gs[NGROUP];
#pragma unroll
        for (int g = 0; g < NGROUP; ++g) {
            float m1 = -1e30f, m2 = -1e30f;
            for (int j = 0; j < 32; ++j) {
                const int e = g * 32 + j;
                const float v = SC[e * 32 + (t ^ (e >> 3))];
                if (v > m1) { m2 = m1; m1 = v; }
                else if (v > m2) { m2 = v; }
            }
            gs[g] = m1 + m2;
        }
        unsigned gmask = 0;
        for (int r = 0; r < TOPKG; ++r) {
            int bi = 0; float bv = -1e30f;
#pragma unroll
            for (int g = 0; g < NGROUP; ++g)
                if (!((gmask >> g) & 1u) && gs[g] > bv) { bv = gs[g]; bi = g; }
            gmask |= (1u << bi);
        }
        int glist[TOPKG], ng = 0;
#pragma unroll
        for (int g = 0; g < NGROUP; ++g)
            if ((gmask >> g) & 1u) glist[ng++] = g;
        int eidx[TOPK]; float sval[TOPK];
        unsigned cmask[TOPKG] = {0u, 0u, 0u, 0u};
        float wsum = 0.f;
        for (int r = 0; r < TOPK; ++r) {
            float bv = -1e30f; int bgi = 0, bj = 0;
            for (int gi = 0; gi < TOPKG; ++gi) {
                const int g = glist[gi];
                for (int j = 0; j < 32; ++j) {
                    if ((cmask[gi] >> j) & 1u) continue;
                    const int e = g * 32 + j;
                    const float v = SC[e * 32 + (t ^ (e >> 3))];
                    if (v > bv) { bv = v; bgi = gi; bj = j; }
                }
            }
            cmask[bgi] |= (1u << bj);
            const int e = glist[bgi] * 32 + bj;
            eidx[r] = e;
            const float sig = bv - bias[e];
            sval[r] = sig; wsum += sig;
        }
        const float scale = ROUTED_SCALING / (wsum + 1e-20f);
        const size_t gt = (size_t)(m0 + t);
#pragma unroll
        for (int r = 0; r < TOPK; ++r) {
            out[gt * TOPK + r] = (float)eidx[r];
            out[(size_t)T * TOPK + gt * TOPK + r] = sval[r] * scale;
        }
    }
}

extern "C" void kernel_launch(void* const* d_in, const int* in_sizes, int n_in,
                              void* d_out, int out_size, void* d_ws, size_t ws_size,
                              hipStream_t stream) {
    const float* X = (const float*)d_in[0];
    const float* W = (const float*)d_in[1];
    const float* B = (const float*)d_in[2];
    float* out = (float*)d_out;
    const int T = in_sizes[0] / H;            // 16384
    if (ws_size >= WS_NEED) {
        wsplit_kernel<<<512, 256, 0, stream>>>(W, (char*)d_ws);
        moe_partial_v4<<<2 * (T / 64), 512, 0, stream>>>(X, (char*)d_ws, T);
        moe_gate_v4<<<T / 64, 256, 0, stream>>>((const char*)d_ws, B, out, T);
    } else if (ws_size >= (size_t)4 * 1024 * 1024) {
        wsplit_kernel<<<512, 256, 0, stream>>>(W, (char*)d_ws);
        moe_mfma_v3<<<T / 64, 512, 0, stream>>>(X, (const char*)d_ws, B, out, T);
    } else {
        moe_gate_f32<<<T / 32, 256, 0, stream>>>(X, W, B, out, T);
    }
}

// Round 11
// 277.823 us; speedup vs baseline: 1.3441x; 1.3441x over previous
//
#include <hip/hip_runtime.h>
#include <hip/hip_bf16.h>

#define H 4096
#define NEXP 256
#define TOPK 8
#define NGROUP 8
#define TOPKG 4
#define ROUTED_SCALING 2.5f
#define WSCALE 1024.0f
#define INV_WSCALE (1.0f / 1024.0f)

#define PART_OFF ((size_t)4 * 1024 * 1024)
#define WS_NEED  (PART_OFF + (size_t)1024 * 32768)   // 4MB wfrags + 32MB partials

typedef __attribute__((ext_vector_type(8)))  _Float16 f16x8;
typedef __attribute__((ext_vector_type(16))) float    f32x16;
typedef __attribute__((ext_vector_type(4)))  float    f32x4;

// ============================================================================
// Pre-kernel: split W*1024 into 2 fp16 levels in 32x32x16 B-fragment order.
// level v at ws + v*2MB; frag addr = ((etile*256+ks)*64+lane)*16.
// ============================================================================
__global__ __launch_bounds__(256) void wsplit_kernel(
    const float* __restrict__ W, char* __restrict__ ws)
{
    const int t  = blockIdx.x * 256 + threadIdx.x;
    const int l  = t & 63;
    const int ks = (t >> 6) & 255;
    const int eg = t >> 14;
    const int expert = eg * 32 + (l & 31);
    const int k0 = ks * 16 + (l >> 5) * 8;
    const float* src = W + (size_t)expert * H + k0;
    float xf[8];
    *(float4*)&xf[0] = *(const float4*)(src);
    *(float4*)&xf[4] = *(const float4*)(src + 4);
    union { _Float16 h[8]; int4 q; } o1, o2;
#pragma unroll
    for (int j = 0; j < 8; ++j) {
        const float x = xf[j] * WSCALE;
        const _Float16 h1 = (_Float16)x;
        o1.h[j] = h1;
        o2.h[j] = (_Float16)(x - (float)h1);
    }
    const size_t off = ((size_t)((eg * 256 + ks) * 64 + l)) * 16;
    *(int4*)(ws + off)           = o1.q;
    *(int4*)(ws + 2097152 + off) = o2.q;
}

// ============================================================================
// Kernel A (v5): 1024 blocks x 512 thr, 2 blocks/CU (16 waves/CU).
// Block (mt = bid>>1, kb = bid&1): 32 tokens x 256 experts x half-K (2048).
// kb = bid&1 constant per XCD (XCD = bid%8) -> per-XCD B working set 2MB =
// half of per-XCD L2 -> W frags L2-resident under the X stream.
// REGISTER BUDGET (round-10 lesson: unified VGPR+AGPR <= 128 at (512,4)):
// m=1 -> acc 48 AGPR + rb 32 + xr 8 + a 8 + addr ~15 VGPR ~= 118. No spill.
// Numerics (proven r5/7/8/9): x1w1 -> acc_hi drained to fp32 tot per 8-step
// slice; x1w2+x2w1 chained in acc_rest (2^-11 scale).
// ============================================================================
__global__ __launch_bounds__(512, 4) void moe_partial_v5(
    const float* __restrict__ X, char* ws, int T)
{
    __shared__ __align__(16) char SM[32768];
    const int tid = threadIdx.x;
    const int l   = tid & 63;
    const int eg  = tid >> 6;        // wave id = expert tile 0..7
    const int sks = tid >> 6;        // staging ks-slot 0..7
    const int bid = blockIdx.x;
    const int kb  = bid & 1;         // K-half
    const int mt  = bid >> 1;        // M-tile (32 tokens)
    const int m0  = mt * 32;

#define XA_OFF(buf, lvl, ks) ((((buf) * 2 + (lvl)) * 8 + (ks)) * 1024)

    const float* Xs_base = X + (size_t)(m0 + (l & 31)) * H
                             + kb * 2048 + sks * 16 + 8 * (l >> 5);
    const char*  bp      = ws + (size_t)eg * 262144
                              + (size_t)(kb * 128) * 1024 + (size_t)l * 16;

    f32x16 acc_hi, acc_rest, tot;
#pragma unroll
    for (int r = 0; r < 16; ++r) { acc_hi[r] = 0.f; acc_rest[r] = 0.f; tot[r] = 0.f; }

    f32x4 xr0, xr1;
    union BF { int4 q; f16x8 v; };
    BF rb[4][2];

#define XISSUE(s)                                                          \
    {   const float* p_ = Xs_base + (size_t)(s) * 128;                     \
        xr0 = __builtin_nontemporal_load((const f32x4*)p_);                \
        xr1 = __builtin_nontemporal_load((const f32x4*)(p_ + 4)); }

#define XWRITE(buf)                                                       \
    {   union { int4 q; _Float16 h[8]; } w1_, w2_;                        \
        _Pragma("unroll")                                                  \
        for (int j = 0; j < 8; ++j) {                                      \
            const float x_ = (j < 4) ? xr0[j] : xr1[j - 4];                \
            const _Float16 h1_ = (_Float16)x_;                             \
            w1_.h[j] = h1_;                                                \
            w2_.h[j] = (_Float16)(x_ - (float)h1_);                        \
        }                                                                  \
        *(int4*)(SM + XA_OFF(buf, 0, sks) + l * 16) = w1_.q;               \
        *(int4*)(SM + XA_OFF(buf, 1, sks) + l * 16) = w2_.q; }

#define SLICE_BARRIER()                                                    \
    { asm volatile("s_waitcnt lgkmcnt(0)" ::: "memory");                   \
      __builtin_amdgcn_s_barrier();                                        \
      asm volatile("" ::: "memory"); }

    XISSUE(0)
    XWRITE(0)
    __syncthreads();
    XISSUE(1)
#pragma unroll
    for (int i = 0; i < 4; ++i) {
        rb[i][0].q = *(const int4*)(bp + (size_t)i * 1024);
        rb[i][1].q = *(const int4*)(bp + 2097152 + (size_t)i * 1024);
    }

    int cur = 0;
    for (int s = 0; s < 16; ++s) {
        const int kbase = s * 8;
#pragma unroll
        for (int i = 0; i < 8; ++i) {
            union { int4 q; f16x8 v; } a1, a2;
            a1.q = *(const int4*)(SM + XA_OFF(cur, 0, i) + l * 16);
            a2.q = *(const int4*)(SM + XA_OFF(cur, 1, i) + l * 16);
            acc_hi = __builtin_amdgcn_mfma_f32_32x32x16_f16(
                a1.v, rb[i & 3][0].v, acc_hi, 0, 0, 0);
            acc_rest = __builtin_amdgcn_mfma_f32_32x32x16_f16(
                a1.v, rb[i & 3][1].v, acc_rest, 0, 0, 0);
            acc_rest = __builtin_amdgcn_mfma_f32_32x32x16_f16(
                a2.v, rb[i & 3][0].v, acc_rest, 0, 0, 0);
            // unconditional prefetch; tail over-read stays inside ws (harmless)
            const int kn = kbase + i + 4;
            rb[i & 3][0].q = *(const int4*)(bp + (size_t)kn * 1024);
            rb[i & 3][1].q = *(const int4*)(bp + 2097152 + (size_t)kn * 1024);
        }
#pragma unroll
        for (int r = 0; r < 16; ++r) { tot[r] += acc_hi[r]; acc_hi[r] = 0.f; }
        if (s + 1 < 16) {
            XWRITE(cur ^ 1)
            SLICE_BARRIER()
            if (s + 2 < 16) XISSUE(s + 2)
            cur ^= 1;
        }
    }
#undef XISSUE
#undef XWRITE
#undef SLICE_BARRIER

    // fp32 partial logits: pp[(eg*16 + r)*64 + l], one 32KB chunk per block
    float* pp = (float*)(ws + PART_OFF) + (size_t)bid * 8192;
#pragma unroll
    for (int r = 0; r < 16; ++r)
        pp[(eg * 16 + r) * 64 + l] = tot[r] + acc_rest[r];
}

// ============================================================================
// Kernel B (v5): 512 blocks x 256 thr, 32 tokens each. Combine both K-half
// partials (fp32 add, commutative -> deterministic), sigmoid+bias into
// swizzled SC, then the proven gating for 32 tokens.
// ============================================================================
__global__ __launch_bounds__(256) void moe_gate_v5(
    const char* __restrict__ ws, const float* __restrict__ bias,
    float* __restrict__ out, int T)
{
    __shared__ float SC[NEXP * 32];   // 32 KB
    const int tid = threadIdx.x;
    const int mt  = blockIdx.x;
    const int m0  = mt * 32;
    const float* p0 = (const float*)(ws + PART_OFF) + (size_t)(mt * 2) * 8192;
    const float* p1 = p0 + 8192;

#pragma unroll 8
    for (int j = 0; j < 32; ++j) {
        const int i  = tid + 256 * j;
        const int l  = i & 63;
        const int r  = (i >> 6) & 15;
        const int eg = i >> 10;
        const int e  = 32 * eg + (l & 31);
        const int ti = (r & 3) + 8 * (r >> 2) + 4 * (l >> 5);
        const float logit = (p0[i] + p1[i]) * INV_WSCALE;
        const float sv = 1.0f / (1.0f + expf(-logit));
        SC[e * 32 + (ti ^ (e & 31))] = sv + bias[e];
    }
    __syncthreads();

    if (tid < 32) {
        const int t = tid;
        float gs[NGROUP];
#pragma unroll
        for (int g = 0; g < NGROUP; ++g) {
            float m1 = -1e30f, m2 = -1e30f;
            for (int j = 0; j < 32; ++j) {
                const int e = g * 32 + j;
                const float v = SC[e * 32 + (t ^ (e & 31))];
                if (v > m1) { m2 = m1; m1 = v; }
                else if (v > m2) { m2 = v; }
            }
            gs[g] = m1 + m2;
        }
        unsigned gmask = 0;
        for (int r = 0; r < TOPKG; ++r) {
            int bi = 0; float bv = -1e30f;
#pragma unroll
            for (int g = 0; g < NGROUP; ++g)
                if (!((gmask >> g) & 1u) && gs[g] > bv) { bv = gs[g]; bi = g; }
            gmask |= (1u << bi);
        }
        int glist[TOPKG], ng = 0;
#pragma unroll
        for (int g = 0; g < NGROUP; ++g)
            if ((gmask >> g) & 1u) glist[ng++] = g;
        int eidx[TOPK]; float sval[TOPK];
        unsigned cmask[TOPKG] = {0u, 0u, 0u, 0u};
        float wsum = 0.f;
        for (int r = 0; r < TOPK; ++r) {
            float bv = -1e30f; int bgi = 0, bj = 0;
            for (int gi = 0; gi < TOPKG; ++gi) {
                const int g = glist[gi];
                for (int j = 0; j < 32; ++j) {
                    if ((cmask[gi] >> j) & 1u) continue;
                    const int e = g * 32 + j;
                    const float v = SC[e * 32 + (t ^ (e & 31))];
                    if (v > bv) { bv = v; bgi = gi; bj = j; }
                }
            }
            cmask[bgi] |= (1u << bj);
            const int e = glist[bgi] * 32 + bj;
            eidx[r] = e;
            const float sig = bv - bias[e];
            sval[r] = sig; wsum += sig;
        }
        const float scale = ROUTED_SCALING / (wsum + 1e-20f);
        const size_t gt = (size_t)(m0 + t);
#pragma unroll
        for (int r = 0; r < TOPK; ++r) {
            out[gt * TOPK + r] = (float)eidx[r];
            out[(size_t)T * TOPK + gt * TOPK + r] = sval[r] * scale;
        }
    }
}

// ============================================================================
// Fallback v3 (verified round-9): 256 blocks x 512 thr, full-K per block.
// ============================================================================
__global__ __launch_bounds__(512, 2) void moe_mfma_v3(
    const float* __restrict__ X, const char* __restrict__ ws,
    const float* __restrict__ bias, float* __restrict__ out, int T)
{
    __shared__ __align__(16) char SM[65536];
    float* SC = (float*)SM;
    const int tid = threadIdx.x;
    const int l   = tid & 63;
    const int eg  = tid >> 6;
    const int sks = tid >> 6;
    const int m0  = blockIdx.x * 64;

#define XA_OFF2(buf, lvl, ks, m) (((((buf) * 2 + (lvl)) * 8 + (ks)) * 2 + (m)) * 1024)

    const float* Xs_base = X + (size_t)(m0 + (l & 31)) * H + sks * 16 + 8 * (l >> 5);
    const char*  bp      = ws + (size_t)eg * 262144 + (size_t)l * 16;

    f32x16 acc_hi[2], acc_rest[2], tot[2];
#pragma unroll
    for (int m = 0; m < 2; ++m)
#pragma unroll
        for (int r = 0; r < 16; ++r) {
            acc_hi[m][r] = 0.f; acc_rest[m][r] = 0.f; tot[m][r] = 0.f;
        }
    f32x4 xr[2][2];
    union BF { int4 q; f16x8 v; };
    BF rb[4][2];

#define XISSUE(s)                                                          \
    { _Pragma("unroll")                                                    \
      for (int m = 0; m < 2; ++m) {                                        \
        const float* p_ = Xs_base + (size_t)(s) * 128 + (size_t)m * 32 * H;\
        xr[m][0] = __builtin_nontemporal_load((const f32x4*)p_);           \
        xr[m][1] = __builtin_nontemporal_load((const f32x4*)(p_ + 4));     \
      } }
#define XWRITE(buf)                                                       \
    { _Pragma("unroll")                                                    \
      for (int m = 0; m < 2; ++m) {                                        \
        union { int4 q; _Float16 h[8]; } w1_, w2_;                        \
        _Pragma("unroll")                                                  \
        for (int j = 0; j < 8; ++j) {                                      \
            const float x_ = (j < 4) ? xr[m][0][j] : xr[m][1][j - 4];      \
            const _Float16 h1_ = (_Float16)x_;                             \
            w1_.h[j] = h1_;                                                \
            w2_.h[j] = (_Float16)(x_ - (float)h1_);                        \
        }                                                                  \
        *(int4*)(SM + XA_OFF2(buf, 0, sks, m) + l * 16) = w1_.q;           \
        *(int4*)(SM + XA_OFF2(buf, 1, sks, m) + l * 16) = w2_.q;           \
      } }
#define SLICE_BARRIER()                                                    \
    { asm volatile("s_waitcnt lgkmcnt(0)" ::: "memory");                   \
      __builtin_amdgcn_s_barrier();                                        \
      asm volatile("" ::: "memory"); }

    XISSUE(0)
    XWRITE(0)
    __syncthreads();
    XISSUE(1)
#pragma unroll
    for (int i = 0; i < 4; ++i) {
        rb[i][0].q = *(const int4*)(bp + (size_t)i * 1024);
        rb[i][1].q = *(const int4*)(bp + 2097152 + (size_t)i * 1024);
    }
    int cur = 0;
    for (int s = 0; s < 32; ++s) {
        const int kbase = s * 8;
#pragma unroll
        for (int i = 0; i < 8; ++i) {
            union { int4 q; f16x8 v; } a1[2], a2[2];
#pragma unroll
            for (int m = 0; m < 2; ++m) {
                a1[m].q = *(const int4*)(SM + XA_OFF2(cur, 0, i, m) + l * 16);
                a2[m].q = *(const int4*)(SM + XA_OFF2(cur, 1, i, m) + l * 16);
            }
#pragma unroll
            for (int m = 0; m < 2; ++m) {
                acc_hi[m] = __builtin_amdgcn_mfma_f32_32x32x16_f16(
                    a1[m].v, rb[i & 3][0].v, acc_hi[m], 0, 0, 0);
                acc_rest[m] = __builtin_amdgcn_mfma_f32_32x32x16_f16(
                    a1[m].v, rb[i & 3][1].v, acc_rest[m], 0, 0, 0);
                acc_rest[m] = __builtin_amdgcn_mfma_f32_32x32x16_f16(
                    a2[m].v, rb[i & 3][0].v, acc_rest[m], 0, 0, 0);
            }
            const int kn = kbase + i + 4;
            if (kn < 256) {
                rb[i & 3][0].q = *(const int4*)(bp + (size_t)kn * 1024);
                rb[i & 3][1].q = *(const int4*)(bp + 2097152 + (size_t)kn * 1024);
            }
        }
#pragma unroll
        for (int m = 0; m < 2; ++m)
#pragma unroll
            for (int r = 0; r < 16; ++r) { tot[m][r] += acc_hi[m][r]; acc_hi[m][r] = 0.f; }
        if (s + 1 < 32) {
            XWRITE(cur ^ 1)
            SLICE_BARRIER()
            if (s + 2 < 32) XISSUE(s + 2)
            cur ^= 1;
        }
    }
#undef XISSUE
#undef XWRITE
#undef SLICE_BARRIER

    __syncthreads();
    {
        const int e = 32 * eg + (l & 31);
        const float be = bias[e];
#pragma unroll
        for (int m = 0; m < 2; ++m)
#pragma unroll
            for (int r = 0; r < 16; ++r) {
                const int ti = 32 * m + (r & 3) + 8 * (r >> 2) + 4 * (l >> 5);
                const float logit = (tot[m][r] + acc_rest[m][r]) * INV_WSCALE;
                const float sv = 1.0f / (1.0f + expf(-logit));
                SC[e * 64 + (ti ^ (e & 31))] = sv + be;
            }
    }
    __syncthreads();
    if (tid < 64) {
        const int t = tid;
        float gs[NGROUP];
#pragma unroll
        for (int g = 0; g < NGROUP; ++g) {
            float m1 = -1e30f, m2 = -1e30f;
            for (int j = 0; j < 32; ++j) {
                const int e = g * 32 + j;
                const float v = SC[e * 64 + (t ^ (e & 31))];
                if (v > m1) { m2 = m1; m1 = v; }
                else if (v > m2) { m2 = v; }
            }
            gs[g] = m1 + m2;
        }
        unsigned gmask = 0;
        for (int r = 0; r < TOPKG; ++r) {
            int bi = 0; float bv = -1e30f;
#pragma unroll
            for (int g = 0; g < NGROUP; ++g)
                if (!((gmask >> g) & 1u) && gs[g] > bv) { bv = gs[g]; bi = g; }
            gmask |= (1u << bi);
        }
        int glist[TOPKG], ng = 0;
#pragma unroll
        for (int g = 0; g < NGROUP; ++g)
            if ((gmask >> g) & 1u) glist[ng++] = g;
        int eidx[TOPK]; float sval[TOPK];
        unsigned cmask[TOPKG] = {0u, 0u, 0u, 0u};
        float wsum = 0.f;
        for (int r = 0; r < TOPK; ++r) {
            float bv = -1e30f; int bgi = 0, bj = 0;
            for (int gi = 0; gi < TOPKG; ++gi) {
                const int g = glist[gi];
                for (int j = 0; j < 32; ++j) {
                    if ((cmask[gi] >> j) & 1u) continue;
                    const int e = g * 32 + j;
                    const float v = SC[e * 64 + (t ^ (e & 31))];
                    if (v > bv) { bv = v; bgi = gi; bj = j; }
                }
            }
            cmask[bgi] |= (1u << bj);
            const int e = glist[bgi] * 32 + bj;
            eidx[r] = e;
            const float sig = bv - bias[e];
            sval[r] = sig; wsum += sig;
        }
        const float scale = ROUTED_SCALING / (wsum + 1e-20f);
        const size_t gt = (size_t)(m0 + t);
#pragma unroll
        for (int r = 0; r < TOPK; ++r) {
            out[gt * TOPK + r] = (float)eidx[r];
            out[(size_t)T * TOPK + gt * TOPK + r] = sval[r] * scale;
        }
    }
}

// ============================================================================
// Fallback (round-3 fp32 kernel) if ws < 4MB.
// ============================================================================
#define BMF 32
#define BKF 32
#define WS_STRIDE 388
#define XS_STRIDE 36
#define WS_FLOATS (BKF * WS_STRIDE)
#define SMEM_FLOATS (WS_FLOATS + BKF * XS_STRIDE)

__global__ __launch_bounds__(256, 2) void moe_gate_f32(
    const float* __restrict__ X, const float* __restrict__ W,
    const float* __restrict__ bias, float* __restrict__ out, int T)
{
    __shared__ float smem[SMEM_FLOATS];
    float* Ws = smem;
    float* Xs = smem + WS_FLOATS;
    float* SC = smem;
    const int tid = threadIdx.x;
    const int tq  = tid >> 5;
    const int tx  = tid & 31;
    const int m0  = blockIdx.x * BMF;
    const int q  = tid & 7;
    const int sx = tid >> 3;
    float acc[4][8];
#pragma unroll
    for (int r = 0; r < 4; ++r)
#pragma unroll
        for (int c = 0; c < 8; ++c) acc[r][c] = 0.f;
    float4 xr, wr[8];
    const float* Xbase = X + (size_t)(m0 + sx) * H + 4 * q;
    const float* Wbase = W + (size_t)sx * H + 4 * q;
    auto loadTile = [&](int k0) {
        xr = *(const float4*)(Xbase + k0);
#pragma unroll
        for (int i = 0; i < 8; ++i)
            wr[i] = *(const float4*)(Wbase + (size_t)(32 * i) * H + k0);
    };
    auto storeTile = [&]() {
        Xs[(4 * q + 0) * XS_STRIDE + sx] = xr.x;
        Xs[(4 * q + 1) * XS_STRIDE + sx] = xr.y;
        Xs[(4 * q + 2) * XS_STRIDE + sx] = xr.z;
        Xs[(4 * q + 3) * XS_STRIDE + sx] = xr.w;
#pragma unroll
        for (int i = 0; i < 8; ++i) {
            const int e = sx + 32 * i;
            const int col = 12 * (e >> 3) + (e & 7);
            Ws[(4 * q + 0) * WS_STRIDE + col] = wr[i].x;
            Ws[(4 * q + 1) * WS_STRIDE + col] = wr[i].y;
            Ws[(4 * q + 2) * WS_STRIDE + col] = wr[i].z;
            Ws[(4 * q + 3) * WS_STRIDE + col] = wr[i].w;
        }
    };
    loadTile(0);
    for (int k0 = 0; k0 < H; k0 += BKF) {
        storeTile();
        __syncthreads();
        if (k0 + BKF < H) loadTile(k0 + BKF);
#pragma unroll 8
        for (int kk = 0; kk < BKF; ++kk) {
            float a[4], b[8];
            *(float4*)&a[0] = *(const float4*)&Xs[kk * XS_STRIDE + 4 * tq];
            *(float4*)&b[0] = *(const float4*)&Ws[kk * WS_STRIDE + 12 * tx];
            *(float4*)&b[4] = *(const float4*)&Ws[kk * WS_STRIDE + 12 * tx + 4];
#pragma unroll
            for (int r = 0; r < 4; ++r)
#pragma unroll
                for (int c = 0; c < 8; ++c)
                    acc[r][c] = fmaf(a[r], b[c], acc[r][c]);
        }
        __syncthreads();
    }
#pragma unroll
    for (int c = 0; c < 8; ++c) {
        const int e = 8 * tx + c;
        const float be = bias[e];
#pragma unroll
        for (int r = 0; r < 4; ++r) {
            const int t = 4 * tq + r;
            const float s = 1.0f / (1.0f + expf(-acc[r][c]));
            SC[e * 32 + (t ^ tx)] = s + be;
        }
    }
    __syncthreads();
    if (tid < BMF) {
        const int t = tid;
        float gs[NGROUP];
#pragma unroll
        for (int g = 0; g < NGROUP; ++g) {
            float m1 = -1e30f, m2 = -1e30f;
            for (int j = 0; j < 32; ++j) {
                const int e = g * 32 + j;
                const float v = SC[e * 32 + (t ^ (e >> 3))];
                if (v > m1) { m2 = m1; m1 = v; }
                else if (v > m2) { m2 = v; }
            }
            gs[g] = m1 + m2;
        }
        unsigned gmask = 0;
        for (int r = 0; r < TOPKG; ++r) {
            int bi = 0; float bv = -1e30f;
#pragma unroll
            for (int g = 0; g < NGROUP; ++g)
                if (!((gmask >> g) & 1u) && gs[g] > bv) { bv = gs[g]; bi = g; }
            gmask |= (1u << bi);
        }
        int glist[TOPKG], ng = 0;
#pragma unroll
        for (int g = 0; g < NGROUP; ++g)
            if ((gmask >> g) & 1u) glist[ng++] = g;
        int eidx[TOPK]; float sval[TOPK];
        unsigned cmask[TOPKG] = {0u, 0u, 0u, 0u};
        float wsum = 0.f;
        for (int r = 0; r < TOPK; ++r) {
            float bv = -1e30f; int bgi = 0, bj = 0;
            for (int gi = 0; gi < TOPKG; ++gi) {
                const int g = glist[gi];
                for (int j = 0; j < 32; ++j) {
                    if ((cmask[gi] >> j) & 1u) continue;
                    const int e = g * 32 + j;
                    const float v = SC[e * 32 + (t ^ (e >> 3))];
                    if (v > bv) { bv = v; bgi = gi; bj = j; }
                }
            }
            cmask[bgi] |= (1u << bj);
            const int e = glist[bgi] * 32 + bj;
            eidx[r] = e;
            const float sig = bv - bias[e];
            sval[r] = sig; wsum += sig;
        }
        const float scale = ROUTED_SCALING / (wsum + 1e-20f);
        const size_t gt = (size_t)(m0 + t);
#pragma unroll
        for (int r = 0; r < TOPK; ++r) {
            out[gt * TOPK + r] = (float)eidx[r];
            out[(size_t)T * TOPK + gt * TOPK + r] = sval[r] * scale;
        }
    }
}

extern "C" void kernel_launch(void* const* d_in, const int* in_sizes, int n_in,
                              void* d_out, int out_size, void* d_ws, size_t ws_size,
                              hipStream_t stream) {
    const float* X = (const float*)d_in[0];
    const float* W = (const float*)d_in[1];
    const float* B = (const float*)d_in[2];
    float* out = (float*)d_out;
    const int T = in_sizes[0] / H;            // 16384
    if (ws_size >= WS_NEED) {
        wsplit_kernel<<<512, 256, 0, stream>>>(W, (char*)d_ws);
        moe_partial_v5<<<2 * (T / 32), 512, 0, stream>>>(X, (char*)d_ws, T);
        moe_gate_v5<<<T / 32, 256, 0, stream>>>((const char*)d_ws, B, out, T);
    } else if (ws_size >= (size_t)4 * 1024 * 1024) {
        wsplit_kernel<<<512, 256, 0, stream>>>(W, (char*)d_ws);
        moe_mfma_v3<<<T / 64, 512, 0, stream>>>(X, (const char*)d_ws, B, out, T);
    } else {
        moe_gate_f32<<<T / 32, 256, 0, stream>>>(X, W, B, out, T);
    }
}

// Round 12
// 252.798 us; speedup vs baseline: 1.4772x; 1.0990x over previous
//
#include <hip/hip_runtime.h>
#include <hip/hip_bf16.h>

#define H 4096
#define NEXP 256
#define TOPK 8
#define NGROUP 8
#define TOPKG 4
#define ROUTED_SCALING 2.5f
#define WSCALE 1024.0f
#define INV_WSCALE (1.0f / 1024.0f)

#define PART_OFF ((size_t)4 * 1024 * 1024)
#define WS_NEED  (PART_OFF + (size_t)1024 * 32768)   // 4MB wfrags + 32MB partials

typedef __attribute__((ext_vector_type(8)))  _Float16 f16x8;
typedef __attribute__((ext_vector_type(16))) float    f32x16;
typedef __attribute__((ext_vector_type(4)))  float    f32x4;

// ============================================================================
// Pre-kernel: split W*1024 into 2 fp16 levels, 32x32x16 B-fragment order,
// LEVELS INTERLEAVED per ks: addr = ((eg*256 + ks)*2 + lvl)*1024 + l*16.
// Each K-step's 2KB of B is contiguous -> L2-friendly; per-XCD set 2MB.
// ============================================================================
__global__ __launch_bounds__(256) void wsplit_kernel(
    const float* __restrict__ W, char* __restrict__ ws)
{
    const int t  = blockIdx.x * 256 + threadIdx.x;
    const int l  = t & 63;
    const int ks = (t >> 6) & 255;
    const int eg = t >> 14;
    const int expert = eg * 32 + (l & 31);
    const int k0 = ks * 16 + (l >> 5) * 8;
    const float* src = W + (size_t)expert * H + k0;
    float xf[8];
    *(float4*)&xf[0] = *(const float4*)(src);
    *(float4*)&xf[4] = *(const float4*)(src + 4);
    union { _Float16 h[8]; int4 q; } o1, o2;
#pragma unroll
    for (int j = 0; j < 8; ++j) {
        const float x = xf[j] * WSCALE;
        const _Float16 h1 = (_Float16)x;
        o1.h[j] = h1;
        o2.h[j] = (_Float16)(x - (float)h1);
    }
    const size_t off = ((size_t)((eg * 256 + ks) * 2)) * 1024 + (size_t)l * 16;
    *(int4*)(ws + off)        = o1.q;
    *(int4*)(ws + off + 1024) = o2.q;
}

// ============================================================================
// Kernel A (v6): 1024 blocks x 512 thr (2 blocks/CU, 16 waves/CU).
// Block (mt=bid>>1, kb=bid&1): 32 tokens x 256 experts x half-K. kb constant
// per XCD (XCD=bid%8, 8j even) -> per-XCD B set = 2MB, L2-resident.
// ROUND-11 LESSON: kernel was latency-stalled (MfmaUtil*dur == MFMA floor).
//  - X pipeline now 2 slices deep (named xa/xb sets, static buf parity)
//    -> issue-to-consume ~2 slices >= ~900cyc nt-HBM latency.
//  - B levels interleaved (contiguous 2KB/step).
//  - Partial stores nontemporal, fragment-contiguous (B stays clean in L2).
// Register budget at (512,4) = 128 unified: ~78 VGPR + 48 acc ~= 126. No spill.
// Numerics (proven r5/7/8/9/11): x1w1 -> acc_hi drained to fp32 tot per slice;
// x1w2+x2w1 chained in acc_rest (2^-11 scale).
// ============================================================================
__global__ __launch_bounds__(512, 4) void moe_partial_v6(
    const float* __restrict__ X, char* ws, int T)
{
    __shared__ __align__(16) char SM[32768];
    const int tid = threadIdx.x;
    const int l   = tid & 63;
    const int eg  = tid >> 6;        // wave id = expert tile 0..7
    const int sks = tid >> 6;        // staging ks-slot 0..7
    const int bid = blockIdx.x;
    const int kb  = bid & 1;         // K-half
    const int mt  = bid >> 1;        // M-tile (32 tokens)
    const int m0  = mt * 32;

#define XA_OFF(buf, lvl, ks) ((((buf) * 2 + (lvl)) * 8 + (ks)) * 1024)

    const float* Xs_base = X + (size_t)(m0 + (l & 31)) * H
                             + kb * 2048 + sks * 16 + 8 * (l >> 5);
    const char*  bp      = ws + (size_t)eg * 524288
                              + (size_t)(kb * 128) * 2048 + (size_t)l * 16;

    f32x16 acc_hi, acc_rest, tot;
#pragma unroll
    for (int r = 0; r < 16; ++r) { acc_hi[r] = 0.f; acc_rest[r] = 0.f; tot[r] = 0.f; }

    f32x4 xa0, xa1, xb0, xb1;        // two named X prefetch sets (2-slice-deep)
    union BF { int4 q; f16x8 v; };
    BF rb[4][2];

#define XISSUE_A(s)                                                        \
    {   const float* p_ = Xs_base + (size_t)(s) * 128;                     \
        xa0 = __builtin_nontemporal_load((const f32x4*)p_);                \
        xa1 = __builtin_nontemporal_load((const f32x4*)(p_ + 4)); }
#define XISSUE_B(s)                                                        \
    {   const float* p_ = Xs_base + (size_t)(s) * 128;                     \
        xb0 = __builtin_nontemporal_load((const f32x4*)p_);                \
        xb1 = __builtin_nontemporal_load((const f32x4*)(p_ + 4)); }

#define XWRITE_IMPL(buf, r0, r1)                                           \
    {   union { int4 q; _Float16 h[8]; } w1_, w2_;                         \
        _Pragma("unroll")                                                  \
        for (int j = 0; j < 8; ++j) {                                      \
            const float x_ = (j < 4) ? r0[j] : r1[j - 4];                  \
            const _Float16 h1_ = (_Float16)x_;                             \
            w1_.h[j] = h1_;                                                \
            w2_.h[j] = (_Float16)(x_ - (float)h1_);                        \
        }                                                                  \
        *(int4*)(SM + XA_OFF(buf, 0, sks) + l * 16) = w1_.q;               \
        *(int4*)(SM + XA_OFF(buf, 1, sks) + l * 16) = w2_.q; }
#define XWRITE_A(buf) XWRITE_IMPL(buf, xa0, xa1)
#define XWRITE_B(buf) XWRITE_IMPL(buf, xb0, xb1)

#define SLICE_BARRIER()                                                    \
    { asm volatile("s_waitcnt lgkmcnt(0)" ::: "memory");                   \
      __builtin_amdgcn_s_barrier();                                        \
      asm volatile("" ::: "memory"); }

    // one slice of compute: 8 K-steps from LDS buf, B-ring 4 ahead, then drain
#define STEPS(buf, slice)                                                  \
    {   const int kb8 = (slice) * 8;                                       \
        _Pragma("unroll")                                                  \
        for (int i = 0; i < 8; ++i) {                                      \
            union { int4 q; f16x8 v; } a1, a2;                             \
            a1.q = *(const int4*)(SM + XA_OFF(buf, 0, i) + l * 16);        \
            a2.q = *(const int4*)(SM + XA_OFF(buf, 1, i) + l * 16);        \
            acc_hi = __builtin_amdgcn_mfma_f32_32x32x16_f16(               \
                a1.v, rb[i & 3][0].v, acc_hi, 0, 0, 0);                    \
            acc_rest = __builtin_amdgcn_mfma_f32_32x32x16_f16(             \
                a1.v, rb[i & 3][1].v, acc_rest, 0, 0, 0);                  \
            acc_rest = __builtin_amdgcn_mfma_f32_32x32x16_f16(             \
                a2.v, rb[i & 3][0].v, acc_rest, 0, 0, 0);                  \
            const int kn = kb8 + i + 4;   /* tail over-read stays in ws */ \
            rb[i & 3][0].q = *(const int4*)(bp + (size_t)kn * 2048);       \
            rb[i & 3][1].q = *(const int4*)(bp + (size_t)kn * 2048 + 1024);\
        }                                                                  \
        _Pragma("unroll")                                                  \
        for (int r = 0; r < 16; ++r) { tot[r] += acc_hi[r]; acc_hi[r] = 0.f; } }

    // prologue: slice0 -> buf0; prefetch slices 1 (A) and 2 (B); prime B-ring
    XISSUE_A(0)
    XWRITE_A(0)
    __syncthreads();
    XISSUE_A(1)
    XISSUE_B(2)
#pragma unroll
    for (int i = 0; i < 4; ++i) {
        rb[i][0].q = *(const int4*)(bp + (size_t)i * 2048);
        rb[i][1].q = *(const int4*)(bp + (size_t)i * 2048 + 1024);
    }

    for (int s = 0; s < 16; s += 2) {
        STEPS(0, s)                      // even slice from buf0
        XWRITE_A(1)                      // slice s+1 -> buf1
        SLICE_BARRIER()
        if (s + 3 < 16) XISSUE_A(s + 3)
        STEPS(1, s + 1)                  // odd slice from buf1
        if (s + 2 < 16) {
            XWRITE_B(0)                  // slice s+2 -> buf0
            SLICE_BARRIER()
            if (s + 4 < 16) XISSUE_B(s + 4)
        }
    }
#undef XISSUE_A
#undef XISSUE_B
#undef XWRITE_IMPL
#undef XWRITE_A
#undef XWRITE_B
#undef SLICE_BARRIER
#undef STEPS

    // nontemporal fp32 partial store, fragment-contiguous:
    // pp index = (eg*64 + l)*16 + r  (per-lane 64B contiguous)
    float* pp = (float*)(ws + PART_OFF) + (size_t)bid * 8192
              + (size_t)(eg * 64 + l) * 16;
    union { f32x16 v; f32x4 c[4]; } res;
#pragma unroll
    for (int r = 0; r < 16; ++r) res.v[r] = tot[r] + acc_rest[r];
#pragma unroll
    for (int j = 0; j < 4; ++j)
        __builtin_nontemporal_store(res.c[j], (f32x4*)pp + j);
}

// ============================================================================
// Kernel B (v6): 512 blocks x 256 thr, 32 tokens each. Combine K-half partials
// (fp32 add, commutative -> deterministic), sigmoid+bias into swizzled SC,
// then the proven gating for 32 tokens.
// ============================================================================
__global__ __launch_bounds__(256) void moe_gate_v6(
    const char* __restrict__ ws, const float* __restrict__ bias,
    float* __restrict__ out, int T)
{
    __shared__ float SC[NEXP * 32];   // 32 KB
    const int tid = threadIdx.x;
    const int mt  = blockIdx.x;
    const int m0  = mt * 32;
    const float* p0 = (const float*)(ws + PART_OFF) + (size_t)(mt * 2) * 8192;
    const float* p1 = p0 + 8192;

#pragma unroll 8
    for (int j = 0; j < 32; ++j) {
        const int i  = tid + 256 * j;
        const int r  = i & 15;               // matches store layout
        const int l  = (i >> 4) & 63;
        const int eg = i >> 10;
        const int e  = 32 * eg + (l & 31);
        const int ti = (r & 3) + 8 * (r >> 2) + 4 * (l >> 5);
        const float logit = (p0[i] + p1[i]) * INV_WSCALE;
        const float sv = 1.0f / (1.0f + expf(-logit));
        SC[e * 32 + (ti ^ (e & 31))] = sv + bias[e];
    }
    __syncthreads();

    if (tid < 32) {
        const int t = tid;
        float gs[NGROUP];
#pragma unroll
        for (int g = 0; g < NGROUP; ++g) {
            float m1 = -1e30f, m2 = -1e30f;
            for (int j = 0; j < 32; ++j) {
                const int e = g * 32 + j;
                const float v = SC[e * 32 + (t ^ (e & 31))];
                if (v > m1) { m2 = m1; m1 = v; }
                else if (v > m2) { m2 = v; }
            }
            gs[g] = m1 + m2;
        }
        unsigned gmask = 0;
        for (int r = 0; r < TOPKG; ++r) {
            int bi = 0; float bv = -1e30f;
#pragma unroll
            for (int g = 0; g < NGROUP; ++g)
                if (!((gmask >> g) & 1u) && gs[g] > bv) { bv = gs[g]; bi = g; }
            gmask |= (1u << bi);
        }
        int glist[TOPKG], ng = 0;
#pragma unroll
        for (int g = 0; g < NGROUP; ++g)
            if ((gmask >> g) & 1u) glist[ng++] = g;
        int eidx[TOPK]; float sval[TOPK];
        unsigned cmask[TOPKG] = {0u, 0u, 0u, 0u};
        float wsum = 0.f;
        for (int r = 0; r < TOPK; ++r) {
            float bv = -1e30f; int bgi = 0, bj = 0;
            for (int gi = 0; gi < TOPKG; ++gi) {
                const int g = glist[gi];
                for (int j = 0; j < 32; ++j) {
                    if ((cmask[gi] >> j) & 1u) continue;
                    const int e = g * 32 + j;
                    const float v = SC[e * 32 + (t ^ (e & 31))];
                    if (v > bv) { bv = v; bgi = gi; bj = j; }
                }
            }
            cmask[bgi] |= (1u << bj);
            const int e = glist[bgi] * 32 + bj;
            eidx[r] = e;
            const float sig = bv - bias[e];
            sval[r] = sig; wsum += sig;
        }
        const float scale = ROUTED_SCALING / (wsum + 1e-20f);
        const size_t gt = (size_t)(m0 + t);
#pragma unroll
        for (int r = 0; r < TOPK; ++r) {
            out[gt * TOPK + r] = (float)eidx[r];
            out[(size_t)T * TOPK + gt * TOPK + r] = sval[r] * scale;
        }
    }
}

// ============================================================================
// Fallback (round-3 fp32 kernel, verified) if ws < WS_NEED.
// ============================================================================
#define BMF 32
#define BKF 32
#define WS_STRIDE 388
#define XS_STRIDE 36
#define WS_FLOATS (BKF * WS_STRIDE)
#define SMEM_FLOATS (WS_FLOATS + BKF * XS_STRIDE)

__global__ __launch_bounds__(256, 2) void moe_gate_f32(
    const float* __restrict__ X, const float* __restrict__ W,
    const float* __restrict__ bias, float* __restrict__ out, int T)
{
    __shared__ float smem[SMEM_FLOATS];
    float* Ws = smem;
    float* Xs = smem + WS_FLOATS;
    float* SC = smem;
    const int tid = threadIdx.x;
    const int tq  = tid >> 5;
    const int tx  = tid & 31;
    const int m0  = blockIdx.x * BMF;
    const int q  = tid & 7;
    const int sx = tid >> 3;
    float acc[4][8];
#pragma unroll
    for (int r = 0; r < 4; ++r)
#pragma unroll
        for (int c = 0; c < 8; ++c) acc[r][c] = 0.f;
    float4 xr, wr[8];
    const float* Xbase = X + (size_t)(m0 + sx) * H + 4 * q;
    const float* Wbase = W + (size_t)sx * H + 4 * q;
    auto loadTile = [&](int k0) {
        xr = *(const float4*)(Xbase + k0);
#pragma unroll
        for (int i = 0; i < 8; ++i)
            wr[i] = *(const float4*)(Wbase + (size_t)(32 * i) * H + k0);
    };
    auto storeTile = [&]() {
        Xs[(4 * q + 0) * XS_STRIDE + sx] = xr.x;
        Xs[(4 * q + 1) * XS_STRIDE + sx] = xr.y;
        Xs[(4 * q + 2) * XS_STRIDE + sx] = xr.z;
        Xs[(4 * q + 3) * XS_STRIDE + sx] = xr.w;
#pragma unroll
        for (int i = 0; i < 8; ++i) {
            const int e = sx + 32 * i;
            const int col = 12 * (e >> 3) + (e & 7);
            Ws[(4 * q + 0) * WS_STRIDE + col] = wr[i].x;
            Ws[(4 * q + 1) * WS_STRIDE + col] = wr[i].y;
            Ws[(4 * q + 2) * WS_STRIDE + col] = wr[i].z;
            Ws[(4 * q + 3) * WS_STRIDE + col] = wr[i].w;
        }
    };
    loadTile(0);
    for (int k0 = 0; k0 < H; k0 += BKF) {
        storeTile();
        __syncthreads();
        if (k0 + BKF < H) loadTile(k0 + BKF);
#pragma unroll 8
        for (int kk = 0; kk < BKF; ++kk) {
            float a[4], b[8];
            *(float4*)&a[0] = *(const float4*)&Xs[kk * XS_STRIDE + 4 * tq];
            *(float4*)&b[0] = *(const float4*)&Ws[kk * WS_STRIDE + 12 * tx];
            *(float4*)&b[4] = *(const float4*)&Ws[kk * WS_STRIDE + 12 * tx + 4];
#pragma unroll
            for (int r = 0; r < 4; ++r)
#pragma unroll
                for (int c = 0; c < 8; ++c)
                    acc[r][c] = fmaf(a[r], b[c], acc[r][c]);
        }
        __syncthreads();
    }
#pragma unroll
    for (int c = 0; c < 8; ++c) {
        const int e = 8 * tx + c;
        const float be = bias[e];
#pragma unroll
        for (int r = 0; r < 4; ++r) {
            const int t = 4 * tq + r;
            const float s = 1.0f / (1.0f + expf(-acc[r][c]));
            SC[e * 32 + (t ^ tx)] = s + be;
        }
    }
    __syncthreads();
    if (tid < BMF) {
        const int t = tid;
        float gs[NGROUP];
#pragma unroll
        for (int g = 0; g < NGROUP; ++g) {
            float m1 = -1e30f, m2 = -1e30f;
            for (int j = 0; j < 32; ++j) {
                const int e = g * 32 + j;
                const float v = SC[e * 32 + (t ^ (e >> 3))];
                if (v > m1) { m2 = m1; m1 = v; }
                else if (v > m2) { m2 = v; }
            }
            gs[g] = m1 + m2;
        }
        unsigned gmask = 0;
        for (int r = 0; r < TOPKG; ++r) {
            int bi = 0; float bv = -1e30f;
#pragma unroll
            for (int g = 0; g < NGROUP; ++g)
                if (!((gmask >> g) & 1u) && gs[g] > bv) { bv = gs[g]; bi = g; }
            gmask |= (1u << bi);
        }
        int glist[TOPKG], ng = 0;
#pragma unroll
        for (int g = 0; g < NGROUP; ++g)
            if ((gmask >> g) & 1u) glist[ng++] = g;
        int eidx[TOPK]; float sval[TOPK];
        unsigned cmask[TOPKG] = {0u, 0u, 0u, 0u};
        float wsum = 0.f;
        for (int r = 0; r < TOPK; ++r) {
            float bv = -1e30f; int bgi = 0, bj = 0;
            for (int gi = 0; gi < TOPKG; ++gi) {
                const int g = glist[gi];
                for (int j = 0; j < 32; ++j) {
                    if ((cmask[gi] >> j) & 1u) continue;
                    const int e = g * 32 + j;
                    const float v = SC[e * 32 + (t ^ (e >> 3))];
                    if (v > bv) { bv = v; bgi = gi; bj = j; }
                }
            }
            cmask[bgi] |= (1u << bj);
            const int e = glist[bgi] * 32 + bj;
            eidx[r] = e;
            const float sig = bv - bias[e];
            sval[r] = sig; wsum += sig;
        }
        const float scale = ROUTED_SCALING / (wsum + 1e-20f);
        const size_t gt = (size_t)(m0 + t);
#pragma unroll
        for (int r = 0; r < TOPK; ++r) {
            out[gt * TOPK + r] = (float)eidx[r];
            out[(size_t)T * TOPK + gt * TOPK + r] = sval[r] * scale;
        }
    }
}

extern "C" void kernel_launch(void* const* d_in, const int* in_sizes, int n_in,
                              void* d_out, int out_size, void* d_ws, size_t ws_size,
                              hipStream_t stream) {
    const float* X = (const float*)d_in[0];
    const float* W = (const float*)d_in[1];
    const float* B = (const float*)d_in[2];
    float* out = (float*)d_out;
    const int T = in_sizes[0] / H;            // 16384
    if (ws_size >= WS_NEED) {
        wsplit_kernel<<<512, 256, 0, stream>>>(W, (char*)d_ws);
        moe_partial_v6<<<2 * (T / 32), 512, 0, stream>>>(X, (char*)d_ws, T);
        moe_gate_v6<<<T / 32, 256, 0, stream>>>((const char*)d_ws, B, out, T);
    } else {
        moe_gate_f32<<<T / 32, 256, 0, stream>>>(X, W, B, out, T);
    }
}